// Round 6
// baseline (3699.829 us; speedup 1.0000x reference)
//
#include <hip/hip_runtime.h>

// StateSpaceModel: y = scan(h = h@A + x@B) @ C,  B=32 L=2048 D=512.
// All GEMM phases use one LDS-tiled MFMA engine (gld16 w=16 staging, XOR-seg
// swizzle: linear LDS dest + inverse-swizzled global src + swizzled read).
// Launch topology (5 launches total):
//   kt_pack   pack/transpose weights, zero row, zero grid-barrier state
//   kt_cvt    xb = bf16(x)
//   kt_u      u = xb@B              128x128 tile, grid 2048
//   kt_mega   powers + taps + chunk-scan tree + 8 Kogge-Stone rounds,
//             11 phases separated by a hand-rolled device-scope grid barrier
//             (agent-scope atomics + __threadfence; grid 576 <= 4 blk/CU*256)
//   kt_out    y = h0@C + P_{c-1}@(A^{j+1}C)   128x128 tile, grid 2048

using bf16 = __bf16;
typedef __bf16 bf16x8 __attribute__((ext_vector_type(8)));
typedef float  f32x4  __attribute__((ext_vector_type(4)));
typedef unsigned int u32;

constexpr int Dm   = 512;
constexpr int Lseq = 2048;
constexpr int KC   = 8;     // chunk length
constexpr int CH   = 256;   // chunks
constexpr long ME  = (long)Dm * Dm;   // elements per 512x512 matrix
constexpr u32 NB   = 576;   // mega grid size (<= 4 blocks/CU * 256 CU / margin)

__device__ __forceinline__ bf16x8 ld8(const bf16* p) {
  return *reinterpret_cast<const bf16x8*>(p);
}
__device__ __forceinline__ bf16x8 ld8f(const float* p) {
  f32x4 lo = *reinterpret_cast<const f32x4*>(p);
  f32x4 hi = *reinterpret_cast<const f32x4*>(p + 4);
  bf16x8 r;
#pragma unroll
  for (int i = 0; i < 4; ++i) { r[i] = (bf16)lo[i]; r[i + 4] = (bf16)hi[i]; }
  return r;
}
__device__ __forceinline__ f32x4 mfma16(bf16x8 a, bf16x8 b, f32x4 c) {
  return __builtin_amdgcn_mfma_f32_16x16x32_bf16(a, b, c, 0, 0, 0);
}
// async global->LDS, 16B per lane; LDS dest = wave-uniform base + lane*16
__device__ __forceinline__ void gld16(const bf16* g, bf16* l) {
  __builtin_amdgcn_global_load_lds(
      (const __attribute__((address_space(1))) u32*)g,
      (__attribute__((address_space(3))) u32*)l, 16, 0, 0);
}

// sense-reversing grid barrier, device(agent)-scope. All NB blocks call it.
__device__ __forceinline__ void gbar(u32* cnt, u32* gen) {
  __syncthreads();
  if (threadIdx.x == 0) {
    __threadfence();   // release: agent-scope fence (L2 writeback on gfx95x)
    u32 g = __hip_atomic_load(gen, __ATOMIC_RELAXED, __HIP_MEMORY_SCOPE_AGENT);
    u32 a = __hip_atomic_fetch_add(cnt, 1u, __ATOMIC_ACQ_REL,
                                   __HIP_MEMORY_SCOPE_AGENT);
    if (a == NB - 1u) {
      __hip_atomic_store(cnt, 0u, __ATOMIC_RELAXED, __HIP_MEMORY_SCOPE_AGENT);
      __hip_atomic_store(gen, g + 1u, __ATOMIC_RELEASE,
                         __HIP_MEMORY_SCOPE_AGENT);
    } else {
      while (__hip_atomic_load(gen, __ATOMIC_ACQUIRE,
                               __HIP_MEMORY_SCOPE_AGENT) == g)
        __builtin_amdgcn_s_sleep(2);
    }
    __threadfence();   // acquire: invalidate stale clean lines
  }
  __syncthreads();
}

// MFMA step over one staged 64-K x 64-row pair of tiles.
template<int WM, int WN>
__device__ __forceinline__ void mma_step(const bf16* As, const bf16* Bs,
                                         int arow, int brow, int sw, int quad,
                                         f32x4 (&acc)[WM][WN]) {
#pragma unroll
  for (int ks = 0; ks < 2; ++ks) {
    const int sg = ((ks * 4 + quad) ^ sw) * 8;
    bf16x8 a[WM], b[WN];
#pragma unroll
    for (int m = 0; m < WM; ++m) a[m] = ld8(As + arow + m * 1024 + sg);
#pragma unroll
    for (int n = 0; n < WN; ++n) b[n] = ld8(Bs + brow + n * 1024 + sg);
#pragma unroll
    for (int m = 0; m < WM; ++m)
#pragma unroll
      for (int n = 0; n < WN; ++n) acc[m][n] = mfma16(a[m], b[n], acc[m][n]);
  }
}

// ---- pack fp32->bf16: Wt[n][k] = W[k][n] for A/B/C, Abf=A, zero row, bar ----
__global__ __launch_bounds__(256) void kt_pack(
    const float* __restrict__ a, const float* __restrict__ b, const float* __restrict__ c,
    bf16* __restrict__ at, bf16* __restrict__ bt, bf16* __restrict__ ct,
    bf16* __restrict__ abf, bf16* __restrict__ zrow, u32* __restrict__ bar) {
  if (blockIdx.y == 0 && blockIdx.x == 0 && threadIdx.x < 256) {
    reinterpret_cast<int*>(zrow)[threadIdx.x] = 0;  // 1 KB of zeros
    if (threadIdx.x < 2) bar[threadIdx.x] = 0;      // barrier cnt/gen
  }
  int flat = blockIdx.x * 256 + threadIdx.x;
  int n = flat & (Dm - 1);
  int k = flat >> 9;
  const float* s = (blockIdx.y == 0) ? a : (blockIdx.y == 1) ? b : c;
  bf16* d        = (blockIdx.y == 0) ? at : (blockIdx.y == 1) ? bt : ct;
  float v = s[(long)k * Dm + n];
  d[(long)n * Dm + k] = (bf16)v;
  if (blockIdx.y == 0) abf[(long)k * Dm + n] = (bf16)v;
}

// ---- xb = bf16(x), pure streaming pass ----
__global__ __launch_bounds__(256) void kt_cvt(
    const float* __restrict__ x, bf16* __restrict__ xb) {
  const long total = (long)32 * Lseq * Dm;
  for (long i = ((long)blockIdx.x * 256 + threadIdx.x) * 8; i < total;
       i += (long)2048 * 256 * 8)
    *reinterpret_cast<bf16x8*>(xb + i) = ld8f(x + i);
}

// ---- u = xb @ B : 128x128 tile, grid (512, 4) ----
__global__ __launch_bounds__(256) void kt_u(
    const bf16* __restrict__ xb, const bf16* __restrict__ Bt, bf16* __restrict__ u) {
  __shared__ __align__(16) char LDSraw[36864];
  bf16* As = (bf16*)LDSraw;         // [128][64]
  bf16* Bs = As + 128 * 64;
  const int tid = threadIdx.x, wave = tid >> 6, lane = tid & 63;
  const int quad = lane >> 4, l16 = lane & 15;
  const int seg = tid & 7, rr0 = tid >> 3;
  const int m0 = blockIdx.x * 128, n0 = blockIdx.y * 128;
  bf16* aL = As + wave * 512;
  bf16* bL = Bs + wave * 512;
  const int wrB = (wave >> 1) * 64, wcB = (wave & 1) * 64;
  const int arow = (wrB + l16) * 64, brow = (wcB + l16) * 64, sw = l16 & 7;
  f32x4 acc[4][4] = {};
  const bf16* aSrc[4]; const bf16* bSrc[4];
#pragma unroll
  for (int it = 0; it < 4; ++it) {
    int r = it * 32 + rr0;
    int sg = seg ^ (r & 7);
    aSrc[it] = xb + (long)(m0 + r) * Dm + sg * 8;
    bSrc[it] = Bt + (long)(n0 + r) * Dm + sg * 8;
  }
  for (int k0 = 0; k0 < Dm; k0 += 64) {
#pragma unroll
    for (int it = 0; it < 4; ++it) {
      gld16(aSrc[it] + k0, aL + it * 2048);
      gld16(bSrc[it] + k0, bL + it * 2048);
    }
    __syncthreads();
    mma_step<4, 4>(As, Bs, arow, brow, sw, quad, acc);
    __syncthreads();
  }
  // epilogue: bf16 staged [128][136] (+8 pad), full-line bf16x8 stores
  bf16* smB = (bf16*)LDSraw;
#pragma unroll
  for (int m = 0; m < 4; ++m)
#pragma unroll
    for (int n = 0; n < 4; ++n)
#pragma unroll
      for (int r = 0; r < 4; ++r)
        smB[(wrB + m * 16 + quad * 4 + r) * 136 + wcB + n * 16 + l16] =
            (bf16)acc[m][n][r];
  __syncthreads();
#pragma unroll
  for (int it = 0; it < 8; ++it) {
    int chunk = it * 256 + tid;
    int row = chunk >> 4, c16 = chunk & 15;
    bf16x8 v = ld8(&smB[row * 136 + c16 * 8]);
    *reinterpret_cast<bf16x8*>(u + (long)(m0 + row) * Dm + n0 + c16 * 8) = v;
  }
}

// ======================= mega-kernel roles =======================

// 512x512x512 GEMM role: S = P @ B (Pt = B^T rows). 16 blocks per job.
__device__ void dev_mm512(char* LDSraw, int bidr,
                          const bf16* P, const bf16* Pt,
                          bf16* S, bf16* St, bool writeS, bool writeSt) {
  bf16* As = (bf16*)LDSraw;
  bf16* Bs = As + 128 * 64;
  const int tid = threadIdx.x, wave = tid >> 6, lane = tid & 63;
  const int quad = lane >> 4, l16 = lane & 15;
  const int seg = tid & 7, rr0 = tid >> 3;
  const int m0 = (bidr >> 2) * 128, n0 = (bidr & 3) * 128;
  bf16* aL = As + wave * 512;
  bf16* bL = Bs + wave * 512;
  const int wrB = (wave >> 1) * 64, wcB = (wave & 1) * 64;
  const int arow = (wrB + l16) * 64, brow = (wcB + l16) * 64, sw = l16 & 7;
  f32x4 acc[4][4] = {};
  const bf16* aSrc[4]; const bf16* bSrc[4];
#pragma unroll
  for (int it = 0; it < 4; ++it) {
    int r = it * 32 + rr0;
    int sg = seg ^ (r & 7);
    aSrc[it] = P + (long)(m0 + r) * Dm + sg * 8;
    bSrc[it] = Pt + (long)(n0 + r) * Dm + sg * 8;
  }
  for (int k0 = 0; k0 < Dm; k0 += 64) {
#pragma unroll
    for (int it = 0; it < 4; ++it) {
      gld16(aSrc[it] + k0, aL + it * 2048);
      gld16(bSrc[it] + k0, bL + it * 2048);
    }
    __syncthreads();
    mma_step<4, 4>(As, Bs, arow, brow, sw, quad, acc);
    __syncthreads();
  }
#pragma unroll
  for (int m = 0; m < 4; ++m)
#pragma unroll
    for (int n = 0; n < 4; ++n)
#pragma unroll
      for (int r = 0; r < 4; ++r) {
        long mg = m0 + wrB + m * 16 + quad * 4 + r;
        long ng = n0 + wcB + n * 16 + l16;
        float v = acc[m][n][r];
        if (writeS)  S[mg * Dm + ng] = (bf16)v;
        if (writeSt) St[ng * Dm + mg] = (bf16)v;
      }
}

// chunk-scan tree role: hall[b,c,j] = h_base@A^{j-base} + sum u@A^... + u_j
__device__ void dev_tree(char* LDSraw, int xb_, int yb, int j, int base,
                         const bf16* u, bf16* hall, const bf16* At,
                         const bf16* A2t, const bf16* A3t, const bf16* A4t) {
  bf16* As = (bf16*)LDSraw;
  bf16* Bs = As + 128 * 64;
  const int tid = threadIdx.x, wave = tid >> 6, lane = tid & 63;
  const int quad = lane >> 4, l16 = lane & 15;
  const int seg = tid & 7, rr0 = tid >> 3;
  const int m0 = xb_ * 128, n0 = yb * 128;
  const int b = m0 >> 8, c0 = m0 & 255;
  bf16* aL = As + wave * 512;
  bf16* bL = Bs + wave * 512;
  const int wrB = (wave >> 1) * 64, wcB = (wave & 1) * 64;
  const int arow = (wrB + l16) * 64, brow = (wcB + l16) * 64, sw = l16 & 7;
  f32x4 acc[4][4] = {};
  const int nseg = j - base;
  for (int s = 0; s < nseg; ++s) {
    const int p = j - base - s;
    const bf16* tp = (p == 1) ? At : (p == 2) ? A2t : (p == 3) ? A3t : A4t;
    const int tsel = base + s;
    const bf16* srcB = (s == 0 && base > 0) ? hall : u;
    const bf16* aSrc[4]; const bf16* bSrc[4];
#pragma unroll
    for (int it = 0; it < 4; ++it) {
      int r = it * 32 + rr0;
      int sg = seg ^ (r & 7);
      aSrc[it] = srcB + ((long)b * Lseq + (long)(c0 + r) * KC + tsel) * Dm + sg * 8;
      bSrc[it] = tp + (long)(n0 + r) * Dm + sg * 8;
    }
    for (int k0 = 0; k0 < Dm; k0 += 64) {
#pragma unroll
      for (int it = 0; it < 4; ++it) {
        gld16(aSrc[it] + k0, aL + it * 2048);
        gld16(bSrc[it] + k0, bL + it * 2048);
      }
      __syncthreads();
      mma_step<4, 4>(As, Bs, arow, brow, sw, quad, acc);
      __syncthreads();
    }
  }
  // epilogue: two-pass fp32 staging, fused +u_j, full-line bf16x8 stores
  float* sm = (float*)LDSraw;  // [64][128]
  const int wr = wave >> 1;
#pragma unroll
  for (int ppass = 0; ppass < 2; ++ppass) {
    __syncthreads();
    if (wr == ppass) {
#pragma unroll
      for (int m = 0; m < 4; ++m)
#pragma unroll
        for (int n = 0; n < 4; ++n)
#pragma unroll
          for (int r = 0; r < 4; ++r)
            sm[(m * 16 + quad * 4 + r) * 128 + wcB + n * 16 + l16] = acc[m][n][r];
    }
    __syncthreads();
#pragma unroll
    for (int it = 0; it < 4; ++it) {
      int chunk = it * 256 + tid;
      int row = chunk >> 4, cg_ = chunk & 15;
      f32x4 lo = *reinterpret_cast<f32x4*>(&sm[row * 128 + cg_ * 8]);
      f32x4 hi = *reinterpret_cast<f32x4*>(&sm[row * 128 + cg_ * 8 + 4]);
      long gaddr = ((long)b * Lseq + (long)(c0 + ppass * 64 + row) * KC + j) * Dm
                   + n0 + cg_ * 8;
      bf16x8 uv = ld8(u + gaddr);
      bf16x8 o;
#pragma unroll
      for (int i = 0; i < 4; ++i) {
        o[i]     = (bf16)(lo[i] + (float)uv[i]);
        o[i + 4] = (bf16)(hi[i] + (float)uv[i + 4]);
      }
      *reinterpret_cast<bf16x8*>(hall + gaddr) = o;
    }
  }
}

// KS round role: Hout[b,c] = Hin[b,c] + Hin[b,c-shift]@Q. 256 blocks (128x128).
__device__ void dev_ks(char* LDSraw, int bidr, int shift,
                       const bf16* HinB, long sb, long sc, long off0,
                       bf16* Hout, const bf16* Qt, const bf16* zrow) {
  bf16* As = (bf16*)LDSraw;
  bf16* Bs = As + 128 * 64;
  const int tid = threadIdx.x, wave = tid >> 6, lane = tid & 63;
  const int quad = lane >> 4, l16 = lane & 15;
  const int seg = tid & 7, rr0 = tid >> 3;
  const int m0 = (bidr >> 2) * 128, n0 = (bidr & 3) * 128;
  const int b = m0 >> 8, c0 = m0 & 255;
  bf16* aL = As + wave * 512;
  bf16* bL = Bs + wave * 512;
  const int wrB = (wave >> 1) * 64, wcB = (wave & 1) * 64;
  const int arow = (wrB + l16) * 64, brow = (wcB + l16) * 64, sw = l16 & 7;
  f32x4 acc[4][4] = {};
  const bf16* aSrc[4]; const bf16* bSrc[4];
#pragma unroll
  for (int it = 0; it < 4; ++it) {
    int r = it * 32 + rr0;
    int sg = seg ^ (r & 7);
    int c = c0 + r - shift;
    aSrc[it] = (c >= 0) ? HinB + ((long)b * sb + (long)c * sc + off0) * Dm + sg * 8
                        : zrow + sg * 8;
    bSrc[it] = Qt + (long)(n0 + r) * Dm + sg * 8;
  }
  for (int k0 = 0; k0 < Dm; k0 += 64) {
#pragma unroll
    for (int it = 0; it < 4; ++it) {
      gld16(aSrc[it] + k0, aL + it * 2048);
      gld16(bSrc[it] + k0, bL + it * 2048);
    }
    __syncthreads();
    mma_step<4, 4>(As, Bs, arow, brow, sw, quad, acc);
    __syncthreads();
  }
  // epilogue: fp32 stage + add Hin[c], bf16x8 stores
  float* sm = (float*)LDSraw;  // [64][128]
  const int wr = wave >> 1;
#pragma unroll
  for (int ppass = 0; ppass < 2; ++ppass) {
    __syncthreads();
    if (wr == ppass) {
#pragma unroll
      for (int m = 0; m < 4; ++m)
#pragma unroll
        for (int n = 0; n < 4; ++n)
#pragma unroll
          for (int r = 0; r < 4; ++r)
            sm[(m * 16 + quad * 4 + r) * 128 + wcB + n * 16 + l16] = acc[m][n][r];
    }
    __syncthreads();
#pragma unroll
    for (int it = 0; it < 4; ++it) {
      int chunk = it * 256 + tid;
      int row = chunk >> 4, cg_ = chunk & 15;
      f32x4 lo = *reinterpret_cast<f32x4*>(&sm[row * 128 + cg_ * 8]);
      f32x4 hi = *reinterpret_cast<f32x4*>(&sm[row * 128 + cg_ * 8 + 4]);
      int c = c0 + ppass * 64 + row;
      bf16x8 hv = ld8(HinB + ((long)b * sb + (long)c * sc + off0) * Dm + n0 + cg_ * 8);
      bf16x8 o;
#pragma unroll
      for (int i = 0; i < 4; ++i) {
        o[i]     = (bf16)(lo[i] + (float)hv[i]);
        o[i + 4] = (bf16)(hi[i] + (float)hv[i + 4]);
      }
      *reinterpret_cast<bf16x8*>(Hout + ((long)(b * 256 + c)) * Dm + n0 + cg_ * 8) = o;
    }
  }
}

// ---- mega: powers + taps + tree + 8 KS rounds, 11 phases, grid barrier ----
__global__ __launch_bounds__(256, 4) void kt_mega(
    const bf16* __restrict__ u, bf16* __restrict__ hall,
    const bf16* __restrict__ Abf, const bf16* __restrict__ At,
    bf16* __restrict__ pwB,   // interleaved: pw[l]=pwB+l*2*ME, pwT[l]=+ME
    bf16* __restrict__ A3, bf16* __restrict__ A3t,
    bf16* __restrict__ A5, bf16* __restrict__ A6, bf16* __restrict__ A7,
    const bf16* __restrict__ Ct, bf16* __restrict__ Tt,
    const bf16* __restrict__ zrow,
    bf16* __restrict__ P0, bf16* __restrict__ P1, u32* bar) {
  __shared__ __align__(16) char L[32768];
  const int bid = blockIdx.x;
  u32* cnt = bar;  u32* gen = bar + 1;
  auto pw  = [&](int l) { return pwB + (long)l * 2 * ME; };
  auto pwT = [&](int l) { return pwB + (long)l * 2 * ME + ME; };

  // P0: tree j=1 (256) || A^2 (16)
  if (bid < 256) {
    dev_tree(L, bid & 63, bid >> 6, 1, 0, u, hall, At, pwT(0), A3t, pwT(1));
  } else if (bid < 272) {
    dev_mm512(L, bid - 256, Abf, At, pw(0), pwT(0), true, true);
  }
  gbar(cnt, gen);

  // P1: tree j=2,3 (512) || A^3, A^4 (32)
  if (bid < 512) {
    int j = 2 + (bid >> 8);
    dev_tree(L, bid & 63, (bid >> 6) & 3, j, 1, u, hall, At, pwT(0), A3t, pwT(1));
  } else if (bid < 544) {
    int q = (bid - 512) >> 4, br = (bid - 512) & 15;
    if (q == 0) dev_mm512(L, br, pw(0), At, A3, A3t, true, true);
    else        dev_mm512(L, br, pw(0), pwT(0), pw(1), pwT(1), true, true);
  }
  gbar(cnt, gen);

  // P2: tree j=4..7 (512 blocks, 2 j's each: {4,7} / {5,6}) || A^5..A^8 (64)
  if (bid < 512) {
    int zb = bid >> 8, x = bid & 63, y = (bid >> 6) & 3;
    dev_tree(L, x, y, 4 + zb, 3, u, hall, At, pwT(0), A3t, pwT(1));
    __syncthreads();
    dev_tree(L, x, y, 7 - zb, 3, u, hall, At, pwT(0), A3t, pwT(1));
  } else {
    int q = (bid - 512) >> 4, br = (bid - 512) & 15;
    if (q == 0)      dev_mm512(L, br, pw(1), At,     A5, nullptr, true, false);
    else if (q == 1) dev_mm512(L, br, pw(1), pwT(0), A6, nullptr, true, false);
    else if (q == 2) dev_mm512(L, br, pw(1), A3t,    A7, nullptr, true, false);
    else             dev_mm512(L, br, pw(1), pwT(1), pw(2), pwT(2), true, true);
  }
  gbar(cnt, gen);

  // P3: KS round 0 (256, hall summaries -> P0) || A^16 (16) || taps (128)
  if (bid < 256) {
    dev_ks(L, bid, 1, hall, (long)Lseq, (long)KC, (long)(KC - 1), P0, pwT(2), zrow);
  } else if (bid < 272) {
    dev_mm512(L, bid - 256, pw(2), pwT(2), pw(3), pwT(3), true, true);
  } else if (bid < 400) {
    int q = (bid - 272) >> 4, br = (bid - 272) & 15;
    const bf16* Aop = (q == 0) ? Abf : (q == 1) ? pw(0) : (q == 2) ? A3
                    : (q == 3) ? pw(1) : (q == 4) ? A5 : (q == 5) ? A6
                    : (q == 6) ? A7 : pw(2);
    dev_mm512(L, br, Aop, Ct, nullptr, Tt + (long)q * ME, false, true);
  }
  gbar(cnt, gen);

  // P4..P10: KS rounds 1..7 (P ping-pong) || folded squaring for next round
  for (int rr = 1; rr < 8; ++rr) {
    const bf16* Hin = (rr & 1) ? P0 : P1;
    bf16* Ho        = (rr & 1) ? P1 : P0;
    if (bid < 256) {
      dev_ks(L, bid, 1 << rr, Hin, 256L, 1L, 0L, Ho, pwT(2 + rr), zrow);
    } else if (bid < 272 && rr < 7) {
      dev_mm512(L, bid - 256, pw(2 + rr), pwT(2 + rr), pw(3 + rr), pwT(3 + rr),
                true, true);
    }
    if (rr != 7) gbar(cnt, gen);   // end-of-kernel release covers the last round
  }
}

// ---- output: y[b,c,j] = h0[b,c,j]@C + P[b,c-1]@T_{j+1}; 128x128 tile ----
__global__ __launch_bounds__(256) void kt_out(
    const bf16* __restrict__ hall, const bf16* __restrict__ u,
    const bf16* __restrict__ P, const bf16* __restrict__ Ct,
    const bf16* __restrict__ Tt, const bf16* __restrict__ zrow,
    float* __restrict__ y) {
  __shared__ __align__(16) char LDSraw[32768];
  bf16* As = (bf16*)LDSraw;         // [128][64]
  bf16* Bs = As + 128 * 64;
  const int tid = threadIdx.x, wave = tid >> 6, lane = tid & 63;
  const int quad = lane >> 4, l16 = lane & 15;
  const int seg = tid & 7, rr0 = tid >> 3;
  const int m0 = blockIdx.x * 128, n0 = blockIdx.y * 128;
  const int j = blockIdx.z;
  const int b = m0 >> 8, c0 = m0 & 255;
  bf16* aL = As + wave * 512;
  bf16* bL = Bs + wave * 512;
  const int wrB = (wave >> 1) * 64, wcB = (wave & 1) * 64;
  const int arow = (wrB + l16) * 64, brow = (wcB + l16) * 64, sw = l16 & 7;
  f32x4 acc[4][4] = {};
  {  // slot A: h0[b,c,j] @ C   (j==0 rows live in u)
    const bf16* H0B = (j == 0) ? u : hall;
    const bf16* aSrc[4]; const bf16* bSrc[4];
#pragma unroll
    for (int it = 0; it < 4; ++it) {
      int r = it * 32 + rr0;
      int sg = seg ^ (r & 7);
      aSrc[it] = H0B + ((long)b * Lseq + (long)(c0 + r) * KC + j) * Dm + sg * 8;
      bSrc[it] = Ct + (long)(n0 + r) * Dm + sg * 8;
    }
    for (int k0 = 0; k0 < Dm; k0 += 64) {
#pragma unroll
      for (int it = 0; it < 4; ++it) {
        gld16(aSrc[it] + k0, aL + it * 2048);
        gld16(bSrc[it] + k0, bL + it * 2048);
      }
      __syncthreads();
      mma_step<4, 4>(As, Bs, arow, brow, sw, quad, acc);
      __syncthreads();
    }
  }
  {  // slot B: P[b,c-1] @ T_{j+1}
    const bf16* Tj = Tt + (long)j * Dm * Dm;
    const bf16* aSrc[4]; const bf16* bSrc[4];
#pragma unroll
    for (int it = 0; it < 4; ++it) {
      int r = it * 32 + rr0;
      int sg = seg ^ (r & 7);
      int c = c0 + r - 1;
      aSrc[it] = (c >= 0) ? P + (long)(b * 256 + c) * Dm + sg * 8 : zrow + sg * 8;
      bSrc[it] = Tj + (long)(n0 + r) * Dm + sg * 8;
    }
    for (int k0 = 0; k0 < Dm; k0 += 64) {
#pragma unroll
      for (int it = 0; it < 4; ++it) {
        gld16(aSrc[it] + k0, aL + it * 2048);
        gld16(bSrc[it] + k0, bL + it * 2048);
      }
      __syncthreads();
      mma_step<4, 4>(As, Bs, arow, brow, sw, quad, acc);
      __syncthreads();
    }
  }
  // epilogue: stage fp32 through LDS (reuse), write 512B-contiguous rows
  float* sm = (float*)LDSraw;  // [64][128]
  const int wr = wave >> 1;
#pragma unroll
  for (int p = 0; p < 2; ++p) {
    __syncthreads();
    if (wr == p) {
#pragma unroll
      for (int m = 0; m < 4; ++m)
#pragma unroll
        for (int n = 0; n < 4; ++n)
#pragma unroll
          for (int r = 0; r < 4; ++r)
            sm[(m * 16 + quad * 4 + r) * 128 + wcB + n * 16 + l16] = acc[m][n][r];
    }
    __syncthreads();
#pragma unroll
    for (int ch = 0; ch < 8; ++ch) {
      int chunk = ch * 256 + tid;
      int srow = chunk >> 5, cc = chunk & 31;
      f32x4 v = *reinterpret_cast<f32x4*>(&sm[srow * 128 + cc * 4]);
      long t = (long)(c0 + p * 64 + srow) * KC + j;
      *reinterpret_cast<f32x4*>(y + ((long)b * Lseq + t) * Dm + n0 + cc * 4) = v;
    }
  }
}

extern "C" void kernel_launch(void* const* d_in, const int* in_sizes, int n_in,
                              void* d_out, int out_size, void* d_ws, size_t ws_size,
                              hipStream_t stream) {
  const float* x  = (const float*)d_in[0];
  const float* dA = (const float*)d_in[1];
  const float* dB = (const float*)d_in[2];
  const float* Cm = (const float*)d_in[3];
  float* out = (float*)d_out;

  char* w = (char*)d_ws;
  const size_t MATB = (size_t)Dm * Dm * sizeof(bf16);  // 512 KB
  bf16* At  = (bf16*)w; w += MATB;
  bf16* Bt  = (bf16*)w; w += MATB;
  bf16* Ct  = (bf16*)w; w += MATB;
  bf16* Abf = (bf16*)w; w += MATB;
  bf16* pwBase = (bf16*)w; w += 20 * MATB;   // pw[l]/pwT[l] interleaved, l=0..9
  bf16* A3  = (bf16*)w; w += MATB;
  bf16* A3t = (bf16*)w; w += MATB;
  bf16* A5  = (bf16*)w; w += MATB;
  bf16* A6  = (bf16*)w; w += MATB;
  bf16* A7  = (bf16*)w; w += MATB;
  bf16* Tt  = (bf16*)w; w += 8 * MATB;                 // taps (A^(j+1) C)^T
  bf16* zrow = (bf16*)w; w += 4096;                    // 512+ zero bf16
  u32* bar  = (u32*)w;  w += 4096;                     // grid barrier cnt/gen
  bf16* u    = (bf16*)w; w += (size_t)32 * Lseq * Dm * sizeof(bf16);  // 64 MB
  bf16* hall = (bf16*)w; w += (size_t)32 * Lseq * Dm * sizeof(bf16);  // 64 MB h0
  bf16* P0 = (bf16*)w; w += (size_t)CH * 32 * Dm * sizeof(bf16);      // 8 MB
  bf16* P1 = (bf16*)w; w += (size_t)CH * 32 * Dm * sizeof(bf16);      // 8 MB
  bf16* xb = hall;   // alias: xb dead before kt_mega first writes hall;
                     // hall j=0 slices are never read (kt_out j==0 uses u)

  // 1. pack + zero row + barrier init; xb = bf16(x)
  kt_pack<<<dim3(Dm * Dm / 256, 3), 256, 0, stream>>>(dA, dB, Cm, At, Bt, Ct,
                                                      Abf, zrow, bar);
  kt_cvt<<<2048, 256, 0, stream>>>(x, xb);
  // 2. u = xb @ deltaB (tiled)
  kt_u<<<dim3(512, 4), 256, 0, stream>>>(xb, Bt, u);
  // 3. mega: powers + taps + tree + 8 KS rounds (final prefixes in P1)
  kt_mega<<<NB, 256, 0, stream>>>(u, hall, Abf, At, pwBase, A3, A3t, A5, A6, A7,
                                  Ct, Tt, zrow, P0, P1, bar);
  // 4. fused output: y = h0@C + P_{c-1}@(A^{j+1}C)
  kt_out<<<dim3(64, 4, 8), 256, 0, stream>>>(hall, u, P1, Ct, Tt, zrow, out);
}